// Round 1
// baseline (194.977 us; speedup 1.0000x reference)
//
#include <hip/hip_runtime.h>
#include <math.h>

#define NN 20000
#define KK 16
#define DD 256
#define VV 64
#define NT1 16
#define SAS 336      // fmm A-tile row stride in bf16 elems

typedef __attribute__((ext_vector_type(8))) __bf16 bf16x8;
typedef __attribute__((ext_vector_type(4))) float floatx4;
typedef __attribute__((ext_vector_type(2))) float floatx2;
typedef __attribute__((ext_vector_type(8))) unsigned short ushort8;
typedef __attribute__((ext_vector_type(4))) unsigned int uint4v;

__device__ __forceinline__ float4 ld4(const float* p) { return *reinterpret_cast<const float4*>(p); }

__device__ __forceinline__ unsigned short f2bf(float f) {
    union { float f; unsigned u; } v; v.f = f;
    unsigned r = v.u + 0x7FFFu + ((v.u >> 16) & 1u);
    return (unsigned short)(r >> 16);
}
__device__ __forceinline__ float bf2f(unsigned short u) {
    union { unsigned u; float f; } v; v.u = ((unsigned)u) << 16;
    return v.f;
}
__device__ __forceinline__ unsigned char f2q(float f) {  // fp8 e4m3, RTNE
    return (unsigned char)(__builtin_amdgcn_cvt_pk_fp8_f32(f, 0.f, 0u, false) & 0xFFu);
}
__device__ __forceinline__ float q2f(unsigned char q) {
    floatx2 r = __builtin_amdgcn_cvt_pk_f32_fp8((unsigned)q, false);
    return r.x;
}
__device__ __forceinline__ float ftanh(float v) {
    float e = __expf(2.f * v);
    return 1.f - 2.f * __builtin_amdgcn_rcpf(e + 1.f);
}

// Launch 1: blocks 0..191 compute EW[layer][v][d] with d=tid (coalesced W reads);
// blocks 192..5191: edge-histogram -> Hc, x -> bf16 (xh), and kld := 0.
__global__ __launch_bounds__(256) void ewhist(
    const int* __restrict__ ie, const float* __restrict__ im,
    const int* __restrict__ oe, const float* __restrict__ om,
    const float* __restrict__ x,
    const float* __restrict__ e1, const float* __restrict__ W1,
    const float* __restrict__ e2, const float* __restrict__ W2,
    const float* __restrict__ e3, const float* __restrict__ W3,
    float* __restrict__ EW, unsigned short* __restrict__ Hc,
    unsigned short* __restrict__ xh, float* __restrict__ kld) {
    int blk = blockIdx.x, tid = threadIdx.x;
    if (blk < 192) {
        int layer = blk >> 6, v = blk & 63, d = tid;
        const float* emb = layer == 0 ? e1 : (layer == 1 ? e2 : e3);
        const float* W   = layer == 0 ? W1 : (layer == 1 ? W2 : W3);
        float acc = 0.f;
        #pragma unroll 8
        for (int j = 0; j < 256; ++j)
            acc += emb[v * DD + j] * W[(size_t)(256 + j) * DD + d];
        EW[(size_t)layer * VV * DD + v * DD + d] = acc;
    } else {
        int pb = blk - 192;
        int w = tid >> 6, lane = tid & 63;
        int n = pb * 4 + w;
        int e = 0; float m = 0.f;
        if (lane < 16)      { e = ie[n * KK + lane];      m = im[n * KK + lane]; }
        else if (lane < 32) { e = oe[n * KK + lane - 16]; m = om[n * KK + lane - 16]; }
        float h = 0.f;
        #pragma unroll
        for (int j = 0; j < 32; ++j) {
            int ev = __shfl(e, j);
            float mv = __shfl(m, j);
            if (ev == lane) h += mv;
        }
        Hc[(size_t)n * 64 + lane] = f2bf(h);
        size_t base = (size_t)pb * 1024 + tid * 4;
        float4 v = ld4(x + base);
        ushort4 o; o.x = f2bf(v.x); o.y = f2bf(v.y); o.z = f2bf(v.z); o.w = f2bf(v.w);
        *reinterpret_cast<ushort4*>(xh + base) = o;
        if (pb == 0 && tid == 0) *kld = 0.f;
    }
}

// Launch 2: pure copy/quantize pack of U1/U23 B-fragments from W and precomputed EW.
__global__ __launch_bounds__(256) void packU(
    const float* __restrict__ W1, const float* __restrict__ W2, const float* __restrict__ W3,
    const float* __restrict__ EW,
    unsigned short* __restrict__ U1, unsigned short* __restrict__ U23) {
    int blk = blockIdx.x, tid = threadIdx.x;
    int u1path = blk < 40;
    int NT = u1path ? 16 : 32;
    int g = (u1path ? blk : blk - 40) * 256 + tid;
    int lane = g & 63, ntk = g >> 6;
    int nt = ntk % NT, kt = ntk / NT;
    if (kt >= 10) return;
    int n = nt * 16 + (lane & 15);
    int kbase = kt * 32 + (lane >> 4) * 8;
    const float* W; const float* EWl;
    if (u1path)       { W = W1; EWl = EW; }
    else if (n < 256) { W = W2; EWl = EW + VV * DD; }
    else              { W = W3; EWl = EW + 2 * VV * DD; n -= 256; }
    unsigned short o8[8];
    #pragma unroll
    for (int j = 0; j < 8; ++j) {
        int k = kbase + j;
        float v = (k < 256) ? W[(size_t)k * DD + n] : EWl[(size_t)(k - 256) * DD + n];
        o8[j] = f2bf(v);
    }
    unsigned short* U = u1path ? U1 : U23;
    *reinterpret_cast<uint4v*>(&U[(size_t)g * 8]) = *reinterpret_cast<uint4v*>(o8);
}

// NEW Launch 3: XCD-pinned quarter-split aggregation for layer 1.
// Grid = (NN/32) * 4. bid&3 selects the 64-col quarter of xh (2.56 MB),
// so with round-robin bid%8 -> XCD, XCD x only ever gathers quarter (x&3):
// the gather working set becomes L2-resident per XCD.
// Each block: 32 nodes; 4 waves x 8 rows/wave; each lane owns one (row, 8-dim)
// slot and accumulates all 32 neighbors (no cross-lane reduce needed).
__global__ __launch_bounds__(256) void agg1(
    const unsigned short* __restrict__ xh,
    const int* __restrict__ ii, const float* __restrict__ im,
    const int* __restrict__ oi, const float* __restrict__ om,
    unsigned short* __restrict__ S) {
    __shared__ int sidx[32][33];   // +1 pad: 8 rows/wave read column j -> spread banks
    __shared__ float smsk[32][33];
    int bid = blockIdx.x;
    int q = bid & 3;
    int n0 = (bid >> 2) * 32;
    int tid = threadIdx.x;
    for (int p = tid; p < 1024; p += 256) {
        int r = p >> 5, j = p & 31;
        int n = n0 + r;
        sidx[r][j] = (j < 16) ? ii[n * KK + j] : oi[n * KK + j - 16];
        smsk[r][j] = (j < 16) ? im[n * KK + j] : om[n * KK + j - 16];
    }
    __syncthreads();
    int lane = tid & 63, w = tid >> 6;
    int row = w * 8 + (lane >> 3);
    int d0 = q * 64 + (lane & 7) * 8;
    float acc[8] = {0.f, 0.f, 0.f, 0.f, 0.f, 0.f, 0.f, 0.f};
    #pragma unroll 8
    for (int j = 0; j < 32; ++j) {
        int idx = sidx[row][j];
        float m = smsk[row][j];
        ushort8 u = *reinterpret_cast<const ushort8*>(xh + (size_t)idx * DD + d0);
        #pragma unroll
        for (int z = 0; z < 8; ++z) acc[z] += m * bf2f(u[z]);
    }
    unsigned short o8[8];
    #pragma unroll
    for (int z = 0; z < 8; ++z) o8[z] = f2bf(acc[z]);
    *reinterpret_cast<uint4v*>(&S[(size_t)(n0 + row) * DD + d0]) =
        *reinterpret_cast<uint4v*>(o8);
}

// Launch 4: slim matmul pass 1: stage S-tile + Hc into LDS, then
// hidden = x + 2*b1 + [S|H] @ U1. Writes f32 out + fp8 copy for the KLD path.
__global__ __launch_bounds__(256) void fmm1b(
    const unsigned short* __restrict__ S, const unsigned short* __restrict__ xh,
    const unsigned short* __restrict__ Hc,
    const unsigned short* __restrict__ U, const float* __restrict__ b,
    float* __restrict__ out, unsigned char* __restrict__ h8) {
    __shared__ unsigned short sA[16 * SAS];
    int n0 = blockIdx.x * 16;
    int tid = threadIdx.x;
    for (int p = tid; p < 512; p += 256) {      // 16 rows x 32 chunks of 16B
        int r = p >> 5, c8 = p & 31;
        *reinterpret_cast<uint4v*>(&sA[r * SAS + c8 * 8]) =
            *reinterpret_cast<const uint4v*>(&S[(size_t)(n0 + r) * DD + c8 * 8]);
    }
    if (tid < 128) {  // stage H cols [256,320)
        int r = tid >> 3, k8 = tid & 7;
        *reinterpret_cast<uint4v*>(&sA[r * SAS + 256 + k8 * 8]) =
            *reinterpret_cast<const uint4v*>(&Hc[(size_t)(n0 + r) * 64 + k8 * 8]);
    }
    __syncthreads();
    int lane = tid & 63, w = tid >> 6;
    int lr = lane & 15, quad = lane >> 4;
    float xp[4][4], bb[4];
    #pragma unroll
    for (int t = 0; t < 4; ++t) {
        int col = (w * 4 + t) * 16 + lr;
        bb[t] = 2.f * b[col];
        #pragma unroll
        for (int r = 0; r < 4; ++r)
            xp[t][r] = bf2f(xh[(size_t)(n0 + quad * 4 + r) * DD + col]);
    }
    floatx4 z = {0.f, 0.f, 0.f, 0.f};
    floatx4 acc[4] = {z, z, z, z};
    for (int kt = 0; kt < 10; ++kt) {
        bf16x8 a = *reinterpret_cast<const bf16x8*>(&sA[lr * SAS + kt * 32 + quad * 8]);
        #pragma unroll
        for (int t = 0; t < 4; ++t) {
            bf16x8 bf = *reinterpret_cast<const bf16x8*>(&U[(size_t)((kt * NT1 + w * 4 + t) * 64 + lane) * 8]);
            acc[t] = __builtin_amdgcn_mfma_f32_16x16x32_bf16(a, bf, acc[t], 0, 0, 0);
        }
    }
    #pragma unroll
    for (int t = 0; t < 4; ++t) {
        int col = (w * 4 + t) * 16 + lr;
        #pragma unroll
        for (int r = 0; r < 4; ++r) {
            size_t o = (size_t)(n0 + quad * 4 + r) * DD + col;
            float v = xp[t][r] + bb[t] + acc[t][r];
            out[o] = v;
            h8[o] = f2q(v);
        }
    }
}

// Fused pass 2 (unchanged this round): fp8 gather of hidden into bf16 LDS A-tile,
// then BOTH mu and logvar bf16 matmuls + fast tanh + KLD atomically accumulated.
__global__ __launch_bounds__(256) void fmm23(const unsigned char* __restrict__ h8, const unsigned short* __restrict__ Hc,
                                             const int* __restrict__ ii, const float* __restrict__ im,
                                             const int* __restrict__ oi, const float* __restrict__ om,
                                             const unsigned short* __restrict__ U, const float* __restrict__ b2,
                                             const float* __restrict__ b3, float* __restrict__ kld) {
    __shared__ unsigned short sA[16 * SAS];
    __shared__ int sidx[16][32];
    __shared__ float smsk[16][32];
    __shared__ float red[4];
    int n0 = blockIdx.x * 16;
    int tid = threadIdx.x;
    for (int q = tid; q < 512; q += 256) {
        int r = q >> 5, j = q & 31;
        int n = n0 + r;
        sidx[r][j] = (j < 16) ? ii[n * KK + j] : oi[n * KK + j - 16];
        smsk[r][j] = (j < 16) ? im[n * KK + j] : om[n * KK + j - 16];
    }
    if (tid < 128) {
        int r = tid >> 3, k8 = tid & 7;
        *reinterpret_cast<uint4v*>(&sA[r * SAS + 256 + k8 * 8]) =
            *reinterpret_cast<const uint4v*>(&Hc[(size_t)(n0 + r) * 64 + k8 * 8]);
    }
    __syncthreads();
    int lane = tid & 63, w = tid >> 6;
    int g = lane >> 4, cl = lane & 15;
    #pragma unroll
    for (int rr = 0; rr < 4; ++rr) {
        int row = w * 4 + rr;
        float acc[16];
        #pragma unroll
        for (int z = 0; z < 16; ++z) acc[z] = 0.f;
        #pragma unroll
        for (int j = 0; j < 8; ++j) {
            int r = g * 8 + j;
            int idx = sidx[row][r];
            float m = smsk[row][r];
            uint4v u = *reinterpret_cast<const uint4v*>(h8 + (size_t)idx * DD + cl * 16);
            #pragma unroll
            for (int d = 0; d < 4; ++d) {
                floatx2 f01 = __builtin_amdgcn_cvt_pk_f32_fp8(u[d], false);
                floatx2 f23 = __builtin_amdgcn_cvt_pk_f32_fp8(u[d], true);
                acc[d * 4 + 0] += m * f01.x; acc[d * 4 + 1] += m * f01.y;
                acc[d * 4 + 2] += m * f23.x; acc[d * 4 + 3] += m * f23.y;
            }
        }
        #pragma unroll
        for (int z = 0; z < 16; ++z) {
            acc[z] += __shfl_xor(acc[z], 16);
            acc[z] += __shfl_xor(acc[z], 32);
        }
        if (g == 0) {
            unsigned short o16[16];
            #pragma unroll
            for (int z = 0; z < 16; ++z) o16[z] = f2bf(acc[z]);
            uint4v* dst = reinterpret_cast<uint4v*>(&sA[row * SAS + cl * 16]);
            dst[0] = reinterpret_cast<uint4v*>(o16)[0];
            dst[1] = reinterpret_cast<uint4v*>(o16)[1];
        }
    }
    __syncthreads();
    int lr = lane & 15, quad = lane >> 4;
    float hp[4][4], bm[4], bl[4];
    #pragma unroll
    for (int t = 0; t < 4; ++t) {
        int col = (w * 4 + t) * 16 + lr;
        bm[t] = 2.f * b2[col];
        bl[t] = 2.f * b3[col];
        #pragma unroll
        for (int r = 0; r < 4; ++r)
            hp[t][r] = q2f(h8[(size_t)(n0 + quad * 4 + r) * DD + col]);
    }
    floatx4 z = {0.f, 0.f, 0.f, 0.f};
    floatx4 am[4] = {z, z, z, z};
    floatx4 al[4] = {z, z, z, z};
    for (int kt = 0; kt < 10; ++kt) {
        bf16x8 a = *reinterpret_cast<const bf16x8*>(&sA[lr * SAS + kt * 32 + quad * 8]);
        #pragma unroll
        for (int t = 0; t < 4; ++t) {
            int nt = w * 4 + t;
            bf16x8 bmu = *reinterpret_cast<const bf16x8*>(&U[(size_t)((kt * 32 + nt) * 64 + lane) * 8]);
            bf16x8 blv = *reinterpret_cast<const bf16x8*>(&U[(size_t)((kt * 32 + 16 + nt) * 64 + lane) * 8]);
            am[t] = __builtin_amdgcn_mfma_f32_16x16x32_bf16(a, bmu, am[t], 0, 0, 0);
            al[t] = __builtin_amdgcn_mfma_f32_16x16x32_bf16(a, blv, al[t], 0, 0, 0);
        }
    }
    float kacc = 0.f;
    #pragma unroll
    for (int t = 0; t < 4; ++t) {
        #pragma unroll
        for (int r = 0; r < 4; ++r) {
            float h = hp[t][r];
            float tm = ftanh(h + bm[t] + am[t][r]);
            float tl = ftanh(h + bl[t] + al[t][r]);
            kacc += (1.f - tm * tm) + (2.f * tl - __expf(2.f * tl));
        }
    }
    #pragma unroll
    for (int off = 32; off > 0; off >>= 1) kacc += __shfl_xor(kacc, off);
    if (lane == 0) red[w] = kacc;
    __syncthreads();
    if (tid == 0)
        atomicAdd(kld, (red[0] + red[1] + red[2] + red[3]) * (-0.5f / ((float)NN * (float)NN)));
}

extern "C" void kernel_launch(void* const* d_in, const int* in_sizes, int n_in,
                              void* d_out, int out_size, void* d_ws, size_t ws_size,
                              hipStream_t stream) {
    const float* x  = (const float*)d_in[0];
    const int*   ii = (const int*)d_in[1];
    const int*   ie = (const int*)d_in[2];
    const float* im = (const float*)d_in[3];
    const int*   oi = (const int*)d_in[4];
    const int*   oe = (const int*)d_in[5];
    const float* om = (const float*)d_in[6];
    const float* e1 = (const float*)d_in[7];
    const float* W1 = (const float*)d_in[8];
    const float* b1 = (const float*)d_in[9];
    const float* e2 = (const float*)d_in[10];
    const float* W2 = (const float*)d_in[11];
    const float* b2 = (const float*)d_in[12];
    const float* e3 = (const float*)d_in[13];
    const float* W3 = (const float*)d_in[14];
    const float* b3 = (const float*)d_in[15];
    float* out = (float*)d_out;
    float* kld = out + (size_t)NN * DD;

    char* ws = (char*)d_ws;
    float*          EW  = (float*)(ws);                     // 3*64*256 f32    (196608 B)
    unsigned short* U1  = (unsigned short*)(ws + 196608);   // 163840 B
    unsigned short* U23 = (unsigned short*)(ws + 360448);   // 327680 B
    unsigned short* Hc  = (unsigned short*)(ws + 688128);   // 20000*64 bf16   (2.56 MB)
    unsigned short* xh  = (unsigned short*)(ws + 3248128);  // 20000*256 bf16  (10.24 MB)
    unsigned char*  h8  = (unsigned char*)(ws + 13488128);  // 20000*256 fp8   (5.12 MB)
    unsigned short* S   = (unsigned short*)(ws + 18608128); // 20000*256 bf16  (10.24 MB)

    ewhist<<<192 + NN / 4, 256, 0, stream>>>(ie, im, oe, om, x, e1, W1, e2, W2, e3, W3,
                                             EW, Hc, xh, kld);
    packU <<<120, 256, 0, stream>>>(W1, W2, W3, EW, U1, U23);
    agg1  <<<(NN / 32) * 4, 256, 0, stream>>>(xh, ii, im, oi, om, S);
    fmm1b <<<NN / 16, 256, 0, stream>>>(S, xh, Hc, U1, b1, out, h8);
    fmm23 <<<NN / 16, 256, 0, stream>>>(h8, Hc, ii, im, oi, om, U23, b2, b3, kld);
}

// Round 2
// 189.151 us; speedup vs baseline: 1.0308x; 1.0308x over previous
//
#include <hip/hip_runtime.h>
#include <math.h>

#define NN 20000
#define KK 16
#define DD 256
#define VV 64
#define NT1 16
#define SAS 336      // fmm A-tile row stride in bf16 elems

typedef __attribute__((ext_vector_type(8))) __bf16 bf16x8;
typedef __attribute__((ext_vector_type(4))) float floatx4;
typedef __attribute__((ext_vector_type(2))) float floatx2;
typedef __attribute__((ext_vector_type(8))) unsigned short ushort8;
typedef __attribute__((ext_vector_type(4))) unsigned int uint4v;

__device__ __forceinline__ float4 ld4(const float* p) { return *reinterpret_cast<const float4*>(p); }

__device__ __forceinline__ unsigned short f2bf(float f) {
    union { float f; unsigned u; } v; v.f = f;
    unsigned r = v.u + 0x7FFFu + ((v.u >> 16) & 1u);
    return (unsigned short)(r >> 16);
}
__device__ __forceinline__ float bf2f(unsigned short u) {
    union { unsigned u; float f; } v; v.u = ((unsigned)u) << 16;
    return v.f;
}
__device__ __forceinline__ float bitf(unsigned u) {
    union { unsigned u; float f; } v; v.u = u;
    return v.f;
}
__device__ __forceinline__ unsigned char f2q(float f) {  // fp8 e4m3, RTNE
    return (unsigned char)(__builtin_amdgcn_cvt_pk_fp8_f32(f, 0.f, 0u, false) & 0xFFu);
}
__device__ __forceinline__ float q2f(unsigned char q) {
    floatx2 r = __builtin_amdgcn_cvt_pk_f32_fp8((unsigned)q, false);
    return r.x;
}
__device__ __forceinline__ float ftanh(float v) {
    float e = __expf(2.f * v);
    return 1.f - 2.f * __builtin_amdgcn_rcpf(e + 1.f);
}

// Launch 1 (packU absorbed):
//   blocks [0,192):   EW row (layer, v) dot-products; scatter the 256 results
//                     DIRECTLY into U1/U23 fragment slots for k = 256+v (kt 8..9).
//   blocks [192,288): pack W-only U fragments (kt 0..7): 32 blocks U1, 64 blocks U23.
//   blocks [288,...): edge-histogram -> Hc, x -> bf16 (xh), kld := 0.
__global__ __launch_bounds__(256) void ewhist(
    const int* __restrict__ ie, const float* __restrict__ im,
    const int* __restrict__ oe, const float* __restrict__ om,
    const float* __restrict__ x,
    const float* __restrict__ e1, const float* __restrict__ W1,
    const float* __restrict__ e2, const float* __restrict__ W2,
    const float* __restrict__ e3, const float* __restrict__ W3,
    unsigned short* __restrict__ U1, unsigned short* __restrict__ U23,
    unsigned short* __restrict__ Hc, unsigned short* __restrict__ xh,
    float* __restrict__ kld) {
    int blk = blockIdx.x, tid = threadIdx.x;
    if (blk < 192) {
        int layer = blk >> 6, v = blk & 63, d = tid;
        const float* emb = layer == 0 ? e1 : (layer == 1 ? e2 : e3);
        const float* W   = layer == 0 ? W1 : (layer == 1 ? W2 : W3);
        float acc = 0.f;
        #pragma unroll 8
        for (int j = 0; j < 256; ++j)
            acc += emb[v * DD + j] * W[(size_t)(256 + j) * DD + d];
        // scatter into U fragment layout: k = 256+v -> kt = 8+(v>>5),
        // lane_hi = (v>>3)&3, j = v&7; n = d.
        unsigned short val = f2bf(acc);
        int j = v & 7, khi = (v >> 3) & 3, kt = 8 + (v >> 5);
        if (layer == 0) {
            int lane = khi * 16 + (d & 15), nt = d >> 4;
            U1[((size_t)(kt * 16 + nt) * 64 + lane) * 8 + j] = val;
        } else {
            int lane = khi * 16 + (d & 15);
            int nt = (layer == 1) ? (d >> 4) : 16 + (d >> 4);
            U23[((size_t)(kt * 32 + nt) * 64 + lane) * 8 + j] = val;
        }
    } else if (blk < 288) {
        int pblk = blk - 192;
        int u1path = pblk < 32;
        int g = (u1path ? pblk : pblk - 32) * 256 + tid;
        int lane = g & 63, ntk = g >> 6;
        int NT = u1path ? 16 : 32;
        int nt = ntk % NT, kt = ntk / NT;          // kt in [0,8) by block count
        int n = nt * 16 + (lane & 15);
        int kbase = kt * 32 + (lane >> 4) * 8;
        const float* W = u1path ? W1 : (n < 256 ? W2 : W3);
        int nn = (n < 256) ? n : n - 256;
        unsigned short o8[8];
        #pragma unroll
        for (int j = 0; j < 8; ++j)
            o8[j] = f2bf(W[(size_t)(kbase + j) * DD + nn]);
        unsigned short* U = u1path ? U1 : U23;
        *reinterpret_cast<uint4v*>(&U[(size_t)g * 8]) = *reinterpret_cast<uint4v*>(o8);
    } else {
        int pb = blk - 288;
        int w = tid >> 6, lane = tid & 63;
        int n = pb * 4 + w;
        int e = 0; float m = 0.f;
        if (lane < 16)      { e = ie[n * KK + lane];      m = im[n * KK + lane]; }
        else if (lane < 32) { e = oe[n * KK + lane - 16]; m = om[n * KK + lane - 16]; }
        float h = 0.f;
        #pragma unroll
        for (int j = 0; j < 32; ++j) {
            int ev = __shfl(e, j);
            float mv = __shfl(m, j);
            if (ev == lane) h += mv;
        }
        Hc[(size_t)n * 64 + lane] = f2bf(h);
        size_t base = (size_t)pb * 1024 + tid * 4;
        float4 v = ld4(x + base);
        ushort4 o; o.x = f2bf(v.x); o.y = f2bf(v.y); o.z = f2bf(v.z); o.w = f2bf(v.w);
        *reinterpret_cast<ushort4*>(xh + base) = o;
        if (pb == 0 && tid == 0) *kld = 0.f;
    }
}

// Launch 2 (fused, R0-proven structure): bf16 gather of x into LDS A-tile
// (now with packed-f32 FMA accumulate), then hidden = x + 2*b1 + [S1|H] @ U1.
// Writes f32 out + fp8 copy for the KLD path.
__global__ __launch_bounds__(256) void fmm1(const unsigned short* __restrict__ xh, const unsigned short* __restrict__ Hc,
                                            const int* __restrict__ ii, const float* __restrict__ im,
                                            const int* __restrict__ oi, const float* __restrict__ om,
                                            const unsigned short* __restrict__ U, const float* __restrict__ b,
                                            float* __restrict__ out, unsigned char* __restrict__ h8) {
    __shared__ unsigned short sA[16 * SAS];
    __shared__ int sidx[16][32];
    __shared__ float smsk[16][32];
    int n0 = blockIdx.x * 16;
    int tid = threadIdx.x;
    for (int q = tid; q < 512; q += 256) {
        int r = q >> 5, j = q & 31;
        int n = n0 + r;
        sidx[r][j] = (j < 16) ? ii[n * KK + j] : oi[n * KK + j - 16];
        smsk[r][j] = (j < 16) ? im[n * KK + j] : om[n * KK + j - 16];
    }
    if (tid < 128) {  // stage H cols [256,320)
        int r = tid >> 3, k8 = tid & 7;
        *reinterpret_cast<uint4v*>(&sA[r * SAS + 256 + k8 * 8]) =
            *reinterpret_cast<const uint4v*>(&Hc[(size_t)(n0 + r) * 64 + k8 * 8]);
    }
    __syncthreads();
    int lane = tid & 63, w = tid >> 6;
    int half = lane >> 5, c = (lane & 31) * 8;
    #pragma unroll
    for (int rr = 0; rr < 4; ++rr) {
        int row = w * 4 + rr;
        floatx2 zz = {0.f, 0.f};
        floatx2 acc2[4] = {zz, zz, zz, zz};
        #pragma unroll
        for (int j = 0; j < 16; ++j) {
            int j2 = j * 2 + half;
            int idx = sidx[row][j2];
            float m = smsk[row][j2];
            floatx2 m2 = {m, m};
            uint4v u = *reinterpret_cast<const uint4v*>(xh + (size_t)idx * DD + c);
            #pragma unroll
            for (int d = 0; d < 4; ++d) {
                unsigned uu = u[d];
                floatx2 p;
                p.x = bitf(uu << 16);
                p.y = bitf(uu & 0xFFFF0000u);
                acc2[d] += m2 * p;    // v_pk_fma_f32
            }
        }
        #pragma unroll
        for (int d = 0; d < 4; ++d) {
            acc2[d].x += __shfl_xor(acc2[d].x, 32);
            acc2[d].y += __shfl_xor(acc2[d].y, 32);
        }
        if (half == 0) {
            unsigned short o8[8];
            #pragma unroll
            for (int d = 0; d < 4; ++d) {
                o8[d * 2]     = f2bf(acc2[d].x);
                o8[d * 2 + 1] = f2bf(acc2[d].y);
            }
            *reinterpret_cast<uint4v*>(&sA[row * SAS + c]) = *reinterpret_cast<uint4v*>(o8);
        }
    }
    __syncthreads();
    int lr = lane & 15, quad = lane >> 4;
    float xp[4][4], bb[4];
    #pragma unroll
    for (int t = 0; t < 4; ++t) {
        int col = (w * 4 + t) * 16 + lr;
        bb[t] = 2.f * b[col];
        #pragma unroll
        for (int r = 0; r < 4; ++r)
            xp[t][r] = bf2f(xh[(size_t)(n0 + quad * 4 + r) * DD + col]);
    }
    floatx4 z = {0.f, 0.f, 0.f, 0.f};
    floatx4 acc[4] = {z, z, z, z};
    for (int kt = 0; kt < 10; ++kt) {
        bf16x8 a = *reinterpret_cast<const bf16x8*>(&sA[lr * SAS + kt * 32 + quad * 8]);
        #pragma unroll
        for (int t = 0; t < 4; ++t) {
            bf16x8 bf = *reinterpret_cast<const bf16x8*>(&U[(size_t)((kt * NT1 + w * 4 + t) * 64 + lane) * 8]);
            acc[t] = __builtin_amdgcn_mfma_f32_16x16x32_bf16(a, bf, acc[t], 0, 0, 0);
        }
    }
    #pragma unroll
    for (int t = 0; t < 4; ++t) {
        int col = (w * 4 + t) * 16 + lr;
        #pragma unroll
        for (int r = 0; r < 4; ++r) {
            size_t o = (size_t)(n0 + quad * 4 + r) * DD + col;
            float v = xp[t][r] + bb[t] + acc[t][r];
            out[o] = v;
            h8[o] = f2q(v);
        }
    }
}

// Launch 3: fp8 gather of hidden into bf16 LDS A-tile (packed-f32 FMA), then BOTH
// mu and logvar bf16 matmuls + fast tanh + KLD atomically accumulated.
__global__ __launch_bounds__(256) void fmm23(const unsigned char* __restrict__ h8, const unsigned short* __restrict__ Hc,
                                             const int* __restrict__ ii, const float* __restrict__ im,
                                             const int* __restrict__ oi, const float* __restrict__ om,
                                             const unsigned short* __restrict__ U, const float* __restrict__ b2,
                                             const float* __restrict__ b3, float* __restrict__ kld) {
    __shared__ unsigned short sA[16 * SAS];
    __shared__ int sidx[16][32];
    __shared__ float smsk[16][32];
    __shared__ float red[4];
    int n0 = blockIdx.x * 16;
    int tid = threadIdx.x;
    for (int q = tid; q < 512; q += 256) {
        int r = q >> 5, j = q & 31;
        int n = n0 + r;
        sidx[r][j] = (j < 16) ? ii[n * KK + j] : oi[n * KK + j - 16];
        smsk[r][j] = (j < 16) ? im[n * KK + j] : om[n * KK + j - 16];
    }
    if (tid < 128) {
        int r = tid >> 3, k8 = tid & 7;
        *reinterpret_cast<uint4v*>(&sA[r * SAS + 256 + k8 * 8]) =
            *reinterpret_cast<const uint4v*>(&Hc[(size_t)(n0 + r) * 64 + k8 * 8]);
    }
    __syncthreads();
    int lane = tid & 63, w = tid >> 6;
    int g = lane >> 4, cl = lane & 15;
    #pragma unroll
    for (int rr = 0; rr < 4; ++rr) {
        int row = w * 4 + rr;
        floatx2 zz = {0.f, 0.f};
        floatx2 acc2[8] = {zz, zz, zz, zz, zz, zz, zz, zz};
        #pragma unroll
        for (int j = 0; j < 8; ++j) {
            int r = g * 8 + j;
            int idx = sidx[row][r];
            float m = smsk[row][r];
            floatx2 m2 = {m, m};
            uint4v u = *reinterpret_cast<const uint4v*>(h8 + (size_t)idx * DD + cl * 16);
            #pragma unroll
            for (int d = 0; d < 4; ++d) {
                floatx2 f01 = __builtin_amdgcn_cvt_pk_f32_fp8(u[d], false);
                floatx2 f23 = __builtin_amdgcn_cvt_pk_f32_fp8(u[d], true);
                acc2[d * 2]     += m2 * f01;   // v_pk_fma_f32
                acc2[d * 2 + 1] += m2 * f23;
            }
        }
        #pragma unroll
        for (int z = 0; z < 8; ++z) {
            acc2[z].x += __shfl_xor(acc2[z].x, 16);
            acc2[z].y += __shfl_xor(acc2[z].y, 16);
            acc2[z].x += __shfl_xor(acc2[z].x, 32);
            acc2[z].y += __shfl_xor(acc2[z].y, 32);
        }
        if (g == 0) {
            unsigned short o16[16];
            #pragma unroll
            for (int d = 0; d < 4; ++d) {
                o16[d * 4 + 0] = f2bf(acc2[d * 2].x);
                o16[d * 4 + 1] = f2bf(acc2[d * 2].y);
                o16[d * 4 + 2] = f2bf(acc2[d * 2 + 1].x);
                o16[d * 4 + 3] = f2bf(acc2[d * 2 + 1].y);
            }
            uint4v* dst = reinterpret_cast<uint4v*>(&sA[row * SAS + cl * 16]);
            dst[0] = reinterpret_cast<uint4v*>(o16)[0];
            dst[1] = reinterpret_cast<uint4v*>(o16)[1];
        }
    }
    __syncthreads();
    int lr = lane & 15, quad = lane >> 4;
    float hp[4][4], bm[4], bl[4];
    #pragma unroll
    for (int t = 0; t < 4; ++t) {
        int col = (w * 4 + t) * 16 + lr;
        bm[t] = 2.f * b2[col];
        bl[t] = 2.f * b3[col];
        #pragma unroll
        for (int r = 0; r < 4; ++r)
            hp[t][r] = q2f(h8[(size_t)(n0 + quad * 4 + r) * DD + col]);
    }
    floatx4 z = {0.f, 0.f, 0.f, 0.f};
    floatx4 am[4] = {z, z, z, z};
    floatx4 al[4] = {z, z, z, z};
    for (int kt = 0; kt < 10; ++kt) {
        bf16x8 a = *reinterpret_cast<const bf16x8*>(&sA[lr * SAS + kt * 32 + quad * 8]);
        #pragma unroll
        for (int t = 0; t < 4; ++t) {
            int nt = w * 4 + t;
            bf16x8 bmu = *reinterpret_cast<const bf16x8*>(&U[(size_t)((kt * 32 + nt) * 64 + lane) * 8]);
            bf16x8 blv = *reinterpret_cast<const bf16x8*>(&U[(size_t)((kt * 32 + 16 + nt) * 64 + lane) * 8]);
            am[t] = __builtin_amdgcn_mfma_f32_16x16x32_bf16(a, bmu, am[t], 0, 0, 0);
            al[t] = __builtin_amdgcn_mfma_f32_16x16x32_bf16(a, blv, al[t], 0, 0, 0);
        }
    }
    float kacc = 0.f;
    #pragma unroll
    for (int t = 0; t < 4; ++t) {
        #pragma unroll
        for (int r = 0; r < 4; ++r) {
            float h = hp[t][r];
            float tm = ftanh(h + bm[t] + am[t][r]);
            float tl = ftanh(h + bl[t] + al[t][r]);
            kacc += (1.f - tm * tm) + (2.f * tl - __expf(2.f * tl));
        }
    }
    #pragma unroll
    for (int off = 32; off > 0; off >>= 1) kacc += __shfl_xor(kacc, off);
    if (lane == 0) red[w] = kacc;
    __syncthreads();
    if (tid == 0)
        atomicAdd(kld, (red[0] + red[1] + red[2] + red[3]) * (-0.5f / ((float)NN * (float)NN)));
}

extern "C" void kernel_launch(void* const* d_in, const int* in_sizes, int n_in,
                              void* d_out, int out_size, void* d_ws, size_t ws_size,
                              hipStream_t stream) {
    const float* x  = (const float*)d_in[0];
    const int*   ii = (const int*)d_in[1];
    const int*   ie = (const int*)d_in[2];
    const float* im = (const float*)d_in[3];
    const int*   oi = (const int*)d_in[4];
    const int*   oe = (const int*)d_in[5];
    const float* om = (const float*)d_in[6];
    const float* e1 = (const float*)d_in[7];
    const float* W1 = (const float*)d_in[8];
    const float* b1 = (const float*)d_in[9];
    const float* e2 = (const float*)d_in[10];
    const float* W2 = (const float*)d_in[11];
    const float* b2 = (const float*)d_in[12];
    const float* e3 = (const float*)d_in[13];
    const float* W3 = (const float*)d_in[14];
    const float* b3 = (const float*)d_in[15];
    float* out = (float*)d_out;
    float* kld = out + (size_t)NN * DD;

    char* ws = (char*)d_ws;
    unsigned short* U1  = (unsigned short*)(ws + 196608);   // 163840 B
    unsigned short* U23 = (unsigned short*)(ws + 360448);   // 327680 B
    unsigned short* Hc  = (unsigned short*)(ws + 688128);   // 20000*64 bf16   (2.56 MB)
    unsigned short* xh  = (unsigned short*)(ws + 3248128);  // 20000*256 bf16  (10.24 MB)
    unsigned char*  h8  = (unsigned char*)(ws + 13488128);  // 20000*256 fp8   (5.12 MB)

    ewhist<<<288 + NN / 4, 256, 0, stream>>>(ie, im, oe, om, x, e1, W1, e2, W2, e3, W3,
                                             U1, U23, Hc, xh, kld);
    fmm1  <<<NN / 16, 256, 0, stream>>>(xh, Hc, ii, im, oi, om, U1, b1, out, h8);
    fmm23 <<<NN / 16, 256, 0, stream>>>(h8, Hc, ii, im, oi, om, U23, b2, b3, kld);
}